// Round 9
// baseline (208.218 us; speedup 1.0000x reference)
//
#include <hip/hip_runtime.h>
#include <hip/hip_cooperative_groups.h>

namespace cg = cooperative_groups;

#define BB 8
#define NN 256
#define FDIM 1024
#define HDIM 256
#define NSQ 65536            // NN*NN
#define ROWS 2048            // BB*NN
#define KSEL 39321           // int(0.6*NN*NN)
#define NBIN 8192            // 13-bit fkey bins
#define LDSW 72              // gemm LDS row stride (bf16 elems)

typedef short s16x8 __attribute__((ext_vector_type(8)));
typedef float f32x4 __attribute__((ext_vector_type(4)));

// ---------- helpers ----------
__device__ __forceinline__ unsigned fkey(float f) {
  unsigned u = __float_as_uint(f);
  return (u & 0x80000000u) ? ~u : (u | 0x80000000u);
}
__device__ __forceinline__ float finv(unsigned k) {
  unsigned u = (k & 0x80000000u) ? (k & 0x7fffffffu) : ~k;
  return __uint_as_float(u);
}
__device__ __forceinline__ unsigned short f2bf(float f) {   // RNE
  unsigned u = __float_as_uint(f);
  unsigned r = (u + 0x7fffu + ((u >> 16) & 1u)) >> 16;
  return (unsigned short)r;
}

// ---------- single cooperative kernel: prep -> gemm -> edge -> out ----------
// 256 blocks x 512 threads; 1 block/CU (LDS 76.8 KB), 8 waves/CU.
__global__ __launch_bounds__(512, 2) void k_fused(
    const float* __restrict__ X, const float* __restrict__ W1,
    const float* __restrict__ b1, const float* __restrict__ W2,
    const float* __restrict__ b2,
    unsigned short* __restrict__ XB, unsigned short* __restrict__ W1B,
    float* __restrict__ PRBT, float* __restrict__ PCT,
    float* __restrict__ edge, unsigned* __restrict__ gcount,
    float* __restrict__ gvsum, float* __restrict__ soft,
    float* __restrict__ causal, float* __restrict__ conf) {
  __shared__ __align__(16) char smem[76800];
  cg::grid_group grid = cg::this_grid();
  const int bx = blockIdx.x, t = threadIdx.x;

  // ================= phase 0: bf16 convert + zero hists =================
  {
    const int g = bx * 512 + t;            // 131072 threads
    {
      const int i16 = g * 16;              // X: 2097152 floats = 131072*16
      float4 v0 = *(const float4*)&X[i16];
      float4 v1 = *(const float4*)&X[i16 + 4];
      float4 v2 = *(const float4*)&X[i16 + 8];
      float4 v3 = *(const float4*)&X[i16 + 12];
      s16x8 o0, o1;
      o0[0] = (short)f2bf(v0.x); o0[1] = (short)f2bf(v0.y); o0[2] = (short)f2bf(v0.z); o0[3] = (short)f2bf(v0.w);
      o0[4] = (short)f2bf(v1.x); o0[5] = (short)f2bf(v1.y); o0[6] = (short)f2bf(v1.z); o0[7] = (short)f2bf(v1.w);
      o1[0] = (short)f2bf(v2.x); o1[1] = (short)f2bf(v2.y); o1[2] = (short)f2bf(v2.z); o1[3] = (short)f2bf(v2.w);
      o1[4] = (short)f2bf(v3.x); o1[5] = (short)f2bf(v3.y); o1[6] = (short)f2bf(v3.z); o1[7] = (short)f2bf(v3.w);
      *(s16x8*)&XB[i16] = o0;
      *(s16x8*)&XB[i16 + 8] = o1;
    }
    if (g < 32768) {
      const int i16 = g * 16;              // W1: 524288 floats = 32768*16
      float4 v0 = *(const float4*)&W1[i16];
      float4 v1 = *(const float4*)&W1[i16 + 4];
      float4 v2 = *(const float4*)&W1[i16 + 8];
      float4 v3 = *(const float4*)&W1[i16 + 12];
      s16x8 o0, o1;
      o0[0] = (short)f2bf(v0.x); o0[1] = (short)f2bf(v0.y); o0[2] = (short)f2bf(v0.z); o0[3] = (short)f2bf(v0.w);
      o0[4] = (short)f2bf(v1.x); o0[5] = (short)f2bf(v1.y); o0[6] = (short)f2bf(v1.z); o0[7] = (short)f2bf(v1.w);
      o1[0] = (short)f2bf(v2.x); o1[1] = (short)f2bf(v2.y); o1[2] = (short)f2bf(v2.z); o1[3] = (short)f2bf(v2.w);
      o1[4] = (short)f2bf(v3.x); o1[5] = (short)f2bf(v3.y); o1[6] = (short)f2bf(v3.z); o1[7] = (short)f2bf(v3.w);
      *(s16x8*)&W1B[i16] = o0;
      *(s16x8*)&W1B[i16 + 8] = o1;
      ((uint4*)gcount)[g] = make_uint4(0u, 0u, 0u, 0u);   // gcount+gvsum contiguous (131072 words)
    }
  }
  grid.sync();

  // ================= phase 1: bf16 MFMA GEMM (transposed out) =================
  {
    short* As = (short*)smem;
    short* Bs = As + 64 * LDSW;
    const int bm = (bx & 31) * 64;
    const int bn = (bx >> 5) * 64;         // 0..448
    const int srow = t >> 3, scg = t & 7;  // 64 rows x 8 col-groups (8 bf16 each)
    const unsigned short* pa = XB + (bm + srow) * FDIM + scg * 8;
    const unsigned short* pb = (bn < 256)
        ? (W1B + (bn + srow) * (2 * FDIM) + scg * 8)
        : (W1B + (bn - 256 + srow) * (2 * FDIM) + FDIM + scg * 8);
    const int w = t >> 6, lane = t & 63;
    const int wr = (w & 3) * 16;           // wave row group (4x16 = 64)
    const int wc = (w >> 2) * 32;          // wave col group (2x32 = 64)
    const int q = lane >> 4, m16 = lane & 15;
    f32x4 acc[2] = {};
    s16x8 ra = *(const s16x8*)(pa);
    s16x8 rb = *(const s16x8*)(pb);
    for (int k0 = 0; k0 < FDIM; k0 += 64) {
      __syncthreads();
      *(s16x8*)&As[srow * LDSW + scg * 8] = ra;
      *(s16x8*)&Bs[srow * LDSW + scg * 8] = rb;
      if (k0 + 64 < FDIM) {                // prefetch next chunk (overlaps MFMA)
        ra = *(const s16x8*)(pa + k0 + 64);
        rb = *(const s16x8*)(pb + k0 + 64);
      }
      __syncthreads();
#pragma unroll
      for (int koff = 0; koff < 64; koff += 32) {
        s16x8 af  = *(s16x8*)&As[(wr + m16) * LDSW + koff + q * 8];
        s16x8 bf0 = *(s16x8*)&Bs[(wc + m16) * LDSW + koff + q * 8];
        s16x8 bf1 = *(s16x8*)&Bs[(wc + 16 + m16) * LDSW + koff + q * 8];
        acc[0] = __builtin_amdgcn_mfma_f32_16x16x32_bf16(af, bf0, acc[0], 0, 0, 0);
        acc[1] = __builtin_amdgcn_mfma_f32_16x16x32_bf16(af, bf1, acc[1], 0, 0, 0);
      }
    }
    // epilogue: D map col=lane&15 (n), row=q*4+reg (m); rows contiguous in PRBT/PCT
#pragma unroll
    for (int ct = 0; ct < 2; ++ct) {
      const int hn = bn + wc + ct * 16 + m16;     // 0..511
      const int row0 = bm + wr + q * 4;
      if (hn < 256) {
        const float bias = b1[hn];
        float4 v = make_float4(acc[ct][0] + bias, acc[ct][1] + bias,
                               acc[ct][2] + bias, acc[ct][3] + bias);
        *(float4*)&PRBT[hn * ROWS + row0] = v;
      } else {
        float4 v = make_float4(acc[ct][0], acc[ct][1], acc[ct][2], acc[ct][3]);
        *(float4*)&PCT[(hn - 256) * ROWS + row0] = v;
      }
    }
  }
  grid.sync();

  // ================= phase 2: edge + 13-bit histogram =================
  float (*prs)[68] = (float(*)[68])smem;                 // 17408 B
  float (*pcs)[36] = (float(*)[36])(smem + 17408);       // 9216 B
  float* w2s       = (float*)(smem + 26624);             // 1024 B
  unsigned* lhc    = (unsigned*)(smem + 27648);          // 16384 B (packed 2x16-bit)
  float* lhv       = (float*)(smem + 44032);             // 32768 B -> 76800 total
  const int b = bx >> 5;
  const int i0 = ((bx >> 3) & 3) * 64, j0 = (bx & 7) * 32;
  const int tmi = t >> 4, tnj = t & 15;
  const int ibase = i0 + tmi * 2, jbase = j0 + tnj * 2;
  float2 ev[2];
  {
    if (t < HDIM) w2s[t] = W2[t];
#pragma unroll
    for (int i = 0; i < 2; ++i) ((uint4*)lhc)[t + i * 512] = make_uint4(0u, 0u, 0u, 0u);
#pragma unroll
    for (int i = 0; i < 4; ++i) ((float4*)lhv)[t + i * 512] = make_float4(0.f, 0.f, 0.f, 0.f);
    const float bias = b2[0];
    float acc[2][2] = {};
    for (int h0 = 0; h0 < HDIM; h0 += 64) {
      __syncthreads();
#pragma unroll
      for (int s = 0; s < 2; ++s) {           // prs: 64h x 64i
        int idx = t + s * 512;
        int hh = idx >> 4, ig = idx & 15;
        *(float4*)&prs[hh][ig * 4] =
            *(const float4*)&PRBT[(h0 + hh) * ROWS + b * NN + i0 + ig * 4];
      }
      {                                       // pcs: 64h x 32j
        int hh = t >> 3, jg = t & 7;
        *(float4*)&pcs[hh][jg * 4] =
            *(const float4*)&PCT[(h0 + hh) * ROWS + b * NN + j0 + jg * 4];
      }
      __syncthreads();
#pragma unroll 8
      for (int h = 0; h < 64; ++h) {
        const float w = w2s[h0 + h];
        const float2 a = *(const float2*)&prs[h][tmi * 2];
        const float2 c = *(const float2*)&pcs[h][tnj * 2];
        acc[0][0] += fmaxf(a.x + c.x, 0.f) * w;
        acc[0][1] += fmaxf(a.x + c.y, 0.f) * w;
        acc[1][0] += fmaxf(a.y + c.x, 0.f) * w;
        acc[1][1] += fmaxf(a.y + c.y, 0.f) * w;
      }
    }
#pragma unroll
    for (int i = 0; i < 2; ++i) {
      float2 v = make_float2(acc[i][0] + bias, acc[i][1] + bias);
      ev[i] = v;
      *(float2*)&edge[b * NSQ + (ibase + i) * NN + jbase] = v;
      float ex = __expf(v.x * 2.f), ey = __expf(v.y * 2.f);
      unsigned bxk = fkey(v.x) >> 19, byk = fkey(v.y) >> 19;
      atomicAdd(&lhc[bxk >> 1], 1u << ((bxk & 1) * 16));
      atomicAdd(&lhv[bxk], ex);
      atomicAdd(&lhc[byk >> 1], 1u << ((byk & 1) * 16));
      atomicAdd(&lhv[byk], ey);
    }
    __syncthreads();
    unsigned* gc = gcount + b * NBIN;
    float* gv = gvsum + b * NBIN;
#pragma unroll
    for (int i = 0; i < 8; ++i) {
      const int idx = t + i * 512;
      unsigned wv = lhc[idx];
      if (wv) {
        unsigned lo = wv & 0xFFFFu, hi = wv >> 16;
        if (lo) atomicAdd(&gc[2 * idx], lo);
        if (hi) atomicAdd(&gc[2 * idx + 1], hi);
      }
    }
#pragma unroll
    for (int i = 0; i < 16; ++i) {
      const int idx = t + i * 512;
      float vv = lhv[idx];
      if (vv != 0.f) atomicAdd(&gv[idx], vv);
    }
  }
  grid.sync();

  // ================= phase 3: scan + outputs (from registers) =================
  {
    unsigned* S = (unsigned*)smem;           // 2048 B
    float* V    = (float*)(smem + 2048);     // 2048 B
    unsigned* ou = (unsigned*)(smem + 4096);
    float* of    = (float*)(smem + 4112);    // [0]=vabove, [1]=vbin, [2]=Z
    const unsigned* hc = gcount + b * NBIN;
    const float* hv = gvsum + b * NBIN;
    unsigned cs = 0; float vs = 0.f;
#pragma unroll
    for (int i = 0; i < 16; ++i) { cs += hc[t * 16 + i]; vs += hv[t * 16 + i]; }
    S[t] = cs; V[t] = vs;
    __syncthreads();
    for (int off = 1; off < 512; off <<= 1) {   // inclusive suffix sums over 512
      unsigned su = (t + off < 512) ? S[t + off] : 0u;
      float vu = (t + off < 512) ? V[t + off] : 0.f;
      __syncthreads();
      S[t] += su; V[t] += vu;
      __syncthreads();
    }
    if (t == 0) of[2] = V[0];                   // Z = total exp sum
    const int above = (int)(S[t] - cs);
    if (above < KSEL && (int)S[t] >= KSEL) {    // exactly one thread
      int cum = above;
      float vcum = V[t] - vs;
      for (int i = 15; i >= 0; --i) {
        unsigned c = hc[t * 16 + i];
        float v = hv[t * 16 + i];
        cum += (int)c;
        if (cum >= KSEL) { ou[0] = (unsigned)(t * 16 + i); of[0] = vcum; of[1] = v; break; }
        vcum += v;
      }
    }
    __syncthreads();
    const float th = finv(ou[0] << 19);         // 13-bit truncated threshold
    const float invZ = 1.f / of[2];
    const float msum = (of[0] + of[1]) * invZ;  // masked soft sum (bin-exact)
    const float invD = 1.f / (msum + 1e-12f);
#pragma unroll
    for (int i = 0; i < 2; ++i) {
      const float2 v = ev[i];
      const int pos = b * NSQ + (ibase + i) * NN + jbase;
      float ox = __expf(v.x * 2.f) * invZ, oy = __expf(v.y * 2.f) * invZ;
      *(float2*)&soft[pos] = make_float2(ox, oy);
      float cx = v.x >= th ? ox * invD : 0.f;
      float cy = v.y >= th ? oy * invD : 0.f;
      *(float2*)&causal[pos] = make_float2(cx, cy);
      *(float2*)&conf[pos]   = make_float2(1.f - cx, 1.f - cy);
    }
  }
}

extern "C" void kernel_launch(void* const* d_in, const int* in_sizes, int n_in,
                              void* d_out, int out_size, void* d_ws, size_t ws_size,
                              hipStream_t stream) {
  const float* x  = (const float*)d_in[0];
  const float* W1 = (const float*)d_in[1];
  const float* b1 = (const float*)d_in[2];
  const float* W2 = (const float*)d_in[3];
  const float* b2 = (const float*)d_in[4];

  float* out = (float*)d_out;
  float* causal = out;
  float* conf   = out + 1 * 524288;
  float* edge   = out + 2 * 524288;
  float* soft   = out + 3 * 524288;

  float* ws = (float*)d_ws;
  float*          PRBT   = ws;                                // 524288 floats
  float*          PCT    = ws + 524288;                       // 524288 floats
  unsigned short* XB     = (unsigned short*)(ws + 1048576);   // 2097152 bf16
  unsigned short* W1B    = (unsigned short*)(ws + 2097152);   // 524288 bf16
  unsigned*       gcount = (unsigned*)(ws + 2359296);         // 8*8192 uints
  float*          gvsum  = (float*)(ws + 2424832);            // 8*8192 floats (contiguous w/ gcount)

  void* args[] = {
    (void*)&x, (void*)&W1, (void*)&b1, (void*)&W2, (void*)&b2,
    (void*)&XB, (void*)&W1B, (void*)&PRBT, (void*)&PCT,
    (void*)&edge, (void*)&gcount, (void*)&gvsum,
    (void*)&soft, (void*)&causal, (void*)&conf
  };
  hipLaunchCooperativeKernel((const void*)k_fused, dim3(256), dim3(512),
                             args, 0, stream);
}

// Round 10
// 114.100 us; speedup vs baseline: 1.8249x; 1.8249x over previous
//
#include <hip/hip_runtime.h>

#define BB 8
#define NN 256
#define FDIM 1024
#define HDIM 256
#define NSQ 65536            // NN*NN
#define ROWS 2048            // BB*NN
#define KSEL 39321           // int(0.6*NN*NN)
#define NBIN 8192            // 13-bit fkey bins
#define LDSW 72              // gemm LDS row stride (bf16 elems)

typedef short s16x8 __attribute__((ext_vector_type(8)));
typedef float f32x4 __attribute__((ext_vector_type(4)));

// ---------- helpers ----------
__device__ __forceinline__ unsigned fkey(float f) {
  unsigned u = __float_as_uint(f);
  return (u & 0x80000000u) ? ~u : (u | 0x80000000u);
}
__device__ __forceinline__ float finv(unsigned k) {
  unsigned u = (k & 0x80000000u) ? (k & 0x7fffffffu) : ~k;
  return __uint_as_float(u);
}
__device__ __forceinline__ unsigned short f2bf(float f) {   // RNE
  unsigned u = __float_as_uint(f);
  unsigned r = (u + 0x7fffu + ((u >> 16) & 1u)) >> 16;
  return (unsigned short)r;
}
__device__ __forceinline__ s16x8 cvt8(float4 lo, float4 hi) {
  s16x8 o;
  o[0] = (short)f2bf(lo.x); o[1] = (short)f2bf(lo.y); o[2] = (short)f2bf(lo.z); o[3] = (short)f2bf(lo.w);
  o[4] = (short)f2bf(hi.x); o[5] = (short)f2bf(hi.y); o[6] = (short)f2bf(hi.z); o[7] = (short)f2bf(hi.w);
  return o;
}

// ---------- K1: bf16-MFMA GEMM (in-kernel fp32->bf16), transposed outputs ----------
// Grid (33, 8): blockIdx.x==32 -> zero gcount/gvsum (131072 words); else GEMM.
// PRBT[h][row] = (x@Wr^T + b1)^T ; PCT[h][row] = (x@Wc^T)^T, row = b*256+n.
__global__ __launch_bounds__(256) void k_gemm(const float* __restrict__ X,
                                              const float* __restrict__ W1,
                                              const float* __restrict__ b1,
                                              float* __restrict__ PRBT,
                                              float* __restrict__ PCT,
                                              unsigned* __restrict__ zero) {
  const int t = threadIdx.x;
  if (blockIdx.x == 32) {                  // 8 zero-blocks (one per y)
    uint4* p = (uint4*)zero + blockIdx.y * 4096 + t;
#pragma unroll
    for (int i = 0; i < 16; ++i) p[i * 256] = make_uint4(0u, 0u, 0u, 0u);
    return;
  }
  const int bm = blockIdx.x * 64;
  const int bn = blockIdx.y * 64;          // 0..448
  __shared__ short As[64 * LDSW];
  __shared__ short Bs[64 * LDSW];
  const int sr = t >> 2, cg = t & 3;       // staging: row 0..63, 16-elem col group
  const float* pa = X + (bm + sr) * FDIM + cg * 16;
  const float* pb = (bn < 256)
      ? (W1 + (bn + sr) * (2 * FDIM) + cg * 16)
      : (W1 + (bn - 256 + sr) * (2 * FDIM) + FDIM + cg * 16);
  const int w = t >> 6, lane = t & 63;
  const int wm = (w >> 1) * 32, wn = (w & 1) * 32;
  const int q = lane >> 4, m16 = lane & 15;
  f32x4 acc[2][2] = {};
  // prefetch iter 0 (fp32)
  float4 a0 = *(const float4*)(pa),      a1 = *(const float4*)(pa + 4);
  float4 a2 = *(const float4*)(pa + 8),  a3 = *(const float4*)(pa + 12);
  float4 w0 = *(const float4*)(pb),      w1 = *(const float4*)(pb + 4);
  float4 w2 = *(const float4*)(pb + 8),  w3 = *(const float4*)(pb + 12);
  for (int k0 = 0; k0 < FDIM; k0 += 64) {
    s16x8 alo = cvt8(a0, a1), ahi = cvt8(a2, a3);
    s16x8 blo = cvt8(w0, w1), bhi = cvt8(w2, w3);
    __syncthreads();
    *(s16x8*)&As[sr * LDSW + cg * 16]     = alo;
    *(s16x8*)&As[sr * LDSW + cg * 16 + 8] = ahi;
    *(s16x8*)&Bs[sr * LDSW + cg * 16]     = blo;
    *(s16x8*)&Bs[sr * LDSW + cg * 16 + 8] = bhi;
    if (k0 + 64 < FDIM) {                  // prefetch next chunk (overlaps MFMA)
      a0 = *(const float4*)(pa + k0 + 64); a1 = *(const float4*)(pa + k0 + 68);
      a2 = *(const float4*)(pa + k0 + 72); a3 = *(const float4*)(pa + k0 + 76);
      w0 = *(const float4*)(pb + k0 + 64); w1 = *(const float4*)(pb + k0 + 68);
      w2 = *(const float4*)(pb + k0 + 72); w3 = *(const float4*)(pb + k0 + 76);
    }
    __syncthreads();
    {
      s16x8 af0 = *(s16x8*)&As[(wm + m16) * LDSW + q * 8];
      s16x8 af1 = *(s16x8*)&As[(wm + 16 + m16) * LDSW + q * 8];
      s16x8 bf0 = *(s16x8*)&Bs[(wn + m16) * LDSW + q * 8];
      s16x8 bf1 = *(s16x8*)&Bs[(wn + 16 + m16) * LDSW + q * 8];
      acc[0][0] = __builtin_amdgcn_mfma_f32_16x16x32_bf16(af0, bf0, acc[0][0], 0, 0, 0);
      acc[0][1] = __builtin_amdgcn_mfma_f32_16x16x32_bf16(af0, bf1, acc[0][1], 0, 0, 0);
      acc[1][0] = __builtin_amdgcn_mfma_f32_16x16x32_bf16(af1, bf0, acc[1][0], 0, 0, 0);
      acc[1][1] = __builtin_amdgcn_mfma_f32_16x16x32_bf16(af1, bf1, acc[1][1], 0, 0, 0);
    }
    {
      s16x8 af0 = *(s16x8*)&As[(wm + m16) * LDSW + 32 + q * 8];
      s16x8 af1 = *(s16x8*)&As[(wm + 16 + m16) * LDSW + 32 + q * 8];
      s16x8 bf0 = *(s16x8*)&Bs[(wn + m16) * LDSW + 32 + q * 8];
      s16x8 bf1 = *(s16x8*)&Bs[(wn + 16 + m16) * LDSW + 32 + q * 8];
      acc[0][0] = __builtin_amdgcn_mfma_f32_16x16x32_bf16(af0, bf0, acc[0][0], 0, 0, 0);
      acc[0][1] = __builtin_amdgcn_mfma_f32_16x16x32_bf16(af0, bf1, acc[0][1], 0, 0, 0);
      acc[1][0] = __builtin_amdgcn_mfma_f32_16x16x32_bf16(af1, bf0, acc[1][0], 0, 0, 0);
      acc[1][1] = __builtin_amdgcn_mfma_f32_16x16x32_bf16(af1, bf1, acc[1][1], 0, 0, 0);
    }
  }
#pragma unroll
  for (int rt = 0; rt < 2; ++rt) {
#pragma unroll
    for (int ct = 0; ct < 2; ++ct) {
      const int hn = bn + wn + ct * 16 + m16;       // 0..511
      const int row0 = bm + wm + rt * 16 + q * 4;
      if (hn < 256) {
        const float bias = b1[hn];
        float4 v = make_float4(acc[rt][ct][0] + bias, acc[rt][ct][1] + bias,
                               acc[rt][ct][2] + bias, acc[rt][ct][3] + bias);
        *(float4*)&PRBT[hn * ROWS + row0] = v;
      } else {
        float4 v = make_float4(acc[rt][ct][0], acc[rt][ct][1],
                               acc[rt][ct][2], acc[rt][ct][3]);
        *(float4*)&PCT[(hn - 256) * ROWS + row0] = v;
      }
    }
  }
}

// ---------- K2: edge + 13-bit count/value histogram ----------
// tile 64(i) x 32(j), 512 threads (8 waves/CU), 2x2 per thread; grid 256.
__global__ __launch_bounds__(512) void k_edge(const float* __restrict__ PRBT,
                                              const float* __restrict__ PCT,
                                              const float* __restrict__ W2,
                                              const float* __restrict__ b2,
                                              float* __restrict__ edge,
                                              unsigned* __restrict__ gcount,
                                              float* __restrict__ gvsum) {
  const int b = blockIdx.z;
  const int i0 = blockIdx.y * 64, j0 = blockIdx.x * 32;
  const int t = threadIdx.x;
  __shared__ float prs[64][68];        // [h][i]
  __shared__ float pcs[64][36];        // [h][j]
  __shared__ float w2s[HDIM];
  __shared__ unsigned lhc[NBIN / 2];   // packed 2x16-bit counts (16 KB)
  __shared__ float lhv[NBIN];          // value sums (32 KB)
  if (t < HDIM) w2s[t] = W2[t];
#pragma unroll
  for (int i = 0; i < 2; ++i) ((uint4*)lhc)[t + i * 512] = make_uint4(0u, 0u, 0u, 0u);
#pragma unroll
  for (int i = 0; i < 4; ++i) ((float4*)lhv)[t + i * 512] = make_float4(0.f, 0.f, 0.f, 0.f);
  const float bias = b2[0];
  const int tmi = t >> 4, tnj = t & 15;     // i-pair 0..31, j-pair 0..15
  float acc[2][2] = {};
  for (int h0 = 0; h0 < HDIM; h0 += 64) {
    __syncthreads();
#pragma unroll
    for (int s = 0; s < 2; ++s) {           // prs: 64h x 64i (1024 float4)
      int idx = t + s * 512;
      int hh = idx >> 4, ig = idx & 15;
      *(float4*)&prs[hh][ig * 4] =
          *(const float4*)&PRBT[(h0 + hh) * ROWS + b * NN + i0 + ig * 4];
    }
    {                                       // pcs: 64h x 32j (512 float4)
      int hh = t >> 3, jg = t & 7;
      *(float4*)&pcs[hh][jg * 4] =
          *(const float4*)&PCT[(h0 + hh) * ROWS + b * NN + j0 + jg * 4];
    }
    __syncthreads();
#pragma unroll 8
    for (int h = 0; h < 64; ++h) {
      const float w = w2s[h0 + h];
      const float2 a = *(const float2*)&prs[h][tmi * 2];
      const float2 c = *(const float2*)&pcs[h][tnj * 2];
      acc[0][0] += fmaxf(a.x + c.x, 0.f) * w;
      acc[0][1] += fmaxf(a.x + c.y, 0.f) * w;
      acc[1][0] += fmaxf(a.y + c.x, 0.f) * w;
      acc[1][1] += fmaxf(a.y + c.y, 0.f) * w;
    }
  }
  // write edge + histogram (values in registers)
  const int ibase = i0 + tmi * 2, jbase = j0 + tnj * 2;
#pragma unroll
  for (int i = 0; i < 2; ++i) {
    float2 v = make_float2(acc[i][0] + bias, acc[i][1] + bias);
    *(float2*)&edge[b * NSQ + (ibase + i) * NN + jbase] = v;
    float ex = __expf(v.x * 2.f), ey = __expf(v.y * 2.f);
    unsigned bx = fkey(v.x) >> 19, by = fkey(v.y) >> 19;
    atomicAdd(&lhc[bx >> 1], 1u << ((bx & 1) * 16));
    atomicAdd(&lhv[bx], ex);
    atomicAdd(&lhc[by >> 1], 1u << ((by & 1) * 16));
    atomicAdd(&lhv[by], ey);
  }
  __syncthreads();
  unsigned* gc = gcount + b * NBIN;
  float* gv = gvsum + b * NBIN;
#pragma unroll
  for (int i = 0; i < 8; ++i) {
    const int idx = t + i * 512;
    unsigned wv = lhc[idx];
    if (wv) {
      unsigned lo = wv & 0xFFFFu, hi = wv >> 16;
      if (lo) atomicAdd(&gc[2 * idx], lo);
      if (hi) atomicAdd(&gc[2 * idx + 1], hi);
    }
  }
#pragma unroll
  for (int i = 0; i < 16; ++i) {
    const int idx = t + i * 512;
    float vv = lhv[idx];
    if (vv != 0.f) atomicAdd(&gv[idx], vv);
  }
}

// ---------- K3: scan (inline) + soft + causal + conf ----------
__global__ __launch_bounds__(256) void k_out(const float* __restrict__ edge,
                                             const unsigned* __restrict__ gcount,
                                             const float* __restrict__ gvsum,
                                             float* __restrict__ soft,
                                             float* __restrict__ causal,
                                             float* __restrict__ conf) {
  const int b = blockIdx.y;
  const int t = threadIdx.x;
  __shared__ unsigned S[256];
  __shared__ float V[256];
  __shared__ unsigned ou[1];
  __shared__ float of[3];
  const unsigned* hc = gcount + b * NBIN;
  const float* hv = gvsum + b * NBIN;
  unsigned cs = 0; float vs = 0.f;
  for (int i = 0; i < 32; ++i) { cs += hc[t * 32 + i]; vs += hv[t * 32 + i]; }
  S[t] = cs; V[t] = vs;
  __syncthreads();
  for (int off = 1; off < 256; off <<= 1) {     // inclusive suffix sums
    unsigned su = (t + off < 256) ? S[t + off] : 0u;
    float vu = (t + off < 256) ? V[t + off] : 0.f;
    __syncthreads();
    S[t] += su; V[t] += vu;
    __syncthreads();
  }
  if (t == 0) of[2] = V[0];                      // Z = total exp sum
  const int above = (int)(S[t] - cs);
  if (above < KSEL && (int)S[t] >= KSEL) {       // exactly one thread
    int cum = above;
    float vcum = V[t] - vs;
    for (int i = 31; i >= 0; --i) {
      unsigned c = hc[t * 32 + i];
      float v = hv[t * 32 + i];
      cum += (int)c;
      if (cum >= KSEL) { ou[0] = (unsigned)(t * 32 + i); of[0] = vcum; of[1] = v; break; }
      vcum += v;
    }
  }
  __syncthreads();
  const float th = finv(ou[0] << 19);            // 13-bit truncated threshold
  const float Z = of[2];
  const float invZ = 1.f / Z;
  const float msum = (of[0] + of[1]) * invZ;     // masked soft sum (bin-exact)
  const float invD = 1.f / (msum + 1e-12f);
  const int off = b * NSQ + blockIdx.x * 2048 + t * 8;
#pragma unroll
  for (int i = 0; i < 8; i += 4) {
    float4 v = *(const float4*)&edge[off + i];
    float4 o = make_float4(__expf(v.x * 2.f) * invZ, __expf(v.y * 2.f) * invZ,
                           __expf(v.z * 2.f) * invZ, __expf(v.w * 2.f) * invZ);
    *(float4*)&soft[off + i] = o;
    float cx = v.x >= th ? o.x * invD : 0.f;
    float cy = v.y >= th ? o.y * invD : 0.f;
    float cz = v.z >= th ? o.z * invD : 0.f;
    float cw = v.w >= th ? o.w * invD : 0.f;
    *(float4*)&causal[off + i] = make_float4(cx, cy, cz, cw);
    *(float4*)&conf[off + i]   = make_float4(1.f - cx, 1.f - cy, 1.f - cz, 1.f - cw);
  }
}

extern "C" void kernel_launch(void* const* d_in, const int* in_sizes, int n_in,
                              void* d_out, int out_size, void* d_ws, size_t ws_size,
                              hipStream_t stream) {
  const float* x  = (const float*)d_in[0];
  const float* W1 = (const float*)d_in[1];
  const float* b1 = (const float*)d_in[2];
  const float* W2 = (const float*)d_in[3];
  const float* b2 = (const float*)d_in[4];

  float* out = (float*)d_out;
  float* causal = out;
  float* conf   = out + 1 * 524288;
  float* edge   = out + 2 * 524288;
  float* soft   = out + 3 * 524288;

  float* ws = (float*)d_ws;
  float*    PRBT   = ws;                          // 524288 floats
  float*    PCT    = ws + 524288;                 // 524288 floats
  unsigned* gcount = (unsigned*)(ws + 1048576);   // 8*8192 uints
  float*    gvsum  = (float*)(ws + 1114112);      // 8*8192 floats (contiguous zero region)

  k_gemm<<<dim3(33, 8), 256, 0, stream>>>(x, W1, b1, PRBT, PCT, gcount);
  k_edge<<<dim3(8, 4, 8), 512, 0, stream>>>(PRBT, PCT, W2, b2, edge, gcount, gvsum);
  k_out<<<dim3(32, 8), 256, 0, stream>>>(edge, gcount, gvsum, soft, causal, conf);
}

// Round 11
// 106.060 us; speedup vs baseline: 1.9632x; 1.0758x over previous
//
#include <hip/hip_runtime.h>

#define BB 8
#define NN 256
#define FDIM 1024
#define HDIM 256
#define NSQ 65536            // NN*NN
#define ROWS 2048            // BB*NN
#define KSEL 39321           // int(0.6*NN*NN)
#define NBIN 8192            // 13-bit fkey bins
#define LDSW 72              // gemm LDS row stride (bf16 elems)

typedef short s16x8 __attribute__((ext_vector_type(8)));
typedef float f32x4 __attribute__((ext_vector_type(4)));

// ---------- helpers ----------
__device__ __forceinline__ unsigned fkey(float f) {
  unsigned u = __float_as_uint(f);
  return (u & 0x80000000u) ? ~u : (u | 0x80000000u);
}
__device__ __forceinline__ float finv(unsigned k) {
  unsigned u = (k & 0x80000000u) ? (k & 0x7fffffffu) : ~k;
  return __uint_as_float(u);
}
__device__ __forceinline__ unsigned short f2bf(float f) {   // RNE
  unsigned u = __float_as_uint(f);
  unsigned r = (u + 0x7fffu + ((u >> 16) & 1u)) >> 16;
  return (unsigned short)r;
}

// ---------- K0: convert X,W1 -> bf16 + zero gcount/gvsum ----------
// grid 1408: [0,1024) X, [1024,1280) W1, [1280,1408) zero (131072 words).
__global__ __launch_bounds__(256) void k_prep(const float* __restrict__ X,
                                              const float* __restrict__ W1,
                                              unsigned short* __restrict__ XB,
                                              unsigned short* __restrict__ W1B,
                                              unsigned* __restrict__ zero) {
  const int bx = blockIdx.x, t = threadIdx.x;
  if (bx < 1280) {
    const float* src = (bx < 1024) ? X : W1;
    unsigned short* dst = (bx < 1024) ? XB : W1B;
    const int idx = ((bx < 1024 ? bx : bx - 1024) * 256 + t) * 8;
    float4 v0 = *(const float4*)&src[idx];
    float4 v1 = *(const float4*)&src[idx + 4];
    s16x8 o;
    o[0] = (short)f2bf(v0.x); o[1] = (short)f2bf(v0.y); o[2] = (short)f2bf(v0.z); o[3] = (short)f2bf(v0.w);
    o[4] = (short)f2bf(v1.x); o[5] = (short)f2bf(v1.y); o[6] = (short)f2bf(v1.z); o[7] = (short)f2bf(v1.w);
    *(s16x8*)&dst[idx] = o;
  } else {
    const int idx = ((bx - 1280) * 256 + t) * 4;
    *(uint4*)&zero[idx] = make_uint4(0u, 0u, 0u, 0u);
  }
}

// ---------- K1: bf16-MFMA GEMM, 64m x 32n tiles, grid (32,16) = 512 blocks ----------
// 2 blocks/CU (LDS 13.8 KB) -> cross-block latency hiding.
// PRBT[h][row] = (x@Wr^T + b1)^T ; PCT[h][row] = (x@Wc^T)^T, row = b*256+n.
__global__ __launch_bounds__(256) void k_gemm(const unsigned short* __restrict__ XB,
                                              const unsigned short* __restrict__ W1B,
                                              const float* __restrict__ b1,
                                              float* __restrict__ PRBT,
                                              float* __restrict__ PCT) {
  const int bm = blockIdx.x * 64;
  const int bn = blockIdx.y * 32;          // 0..480
  const int t = threadIdx.x;
  __shared__ short As[64 * LDSW];
  __shared__ short Bs[32 * LDSW];
  // A staging: row sr 0..63, 16-elem col group cg 0..3 (32 B/thread)
  const int sr = t >> 2, cg = t & 3;
  const unsigned short* pa = XB + (bm + sr) * FDIM + cg * 16;
  // B staging: row srb 0..31, 8-elem col group cgb 0..7 (16 B/thread)
  const int srb = t >> 3, cgb = t & 7;
  const unsigned short* pb = (bn < 256)
      ? (W1B + (bn + srb) * (2 * FDIM) + cgb * 8)
      : (W1B + (bn - 256 + srb) * (2 * FDIM) + FDIM + cgb * 8);
  const int w = t >> 6, lane = t & 63;
  const int wm = (w & 1) * 32, wn = (w >> 1) * 16;   // 4 waves cover 64m x 32n
  const int q = lane >> 4, m16 = lane & 15;
  f32x4 acc[2] = {};
  // prefetch iter 0
  s16x8 ra0 = *(const s16x8*)(pa);
  s16x8 ra1 = *(const s16x8*)(pa + 8);
  s16x8 rb = *(const s16x8*)(pb);
  for (int k0 = 0; k0 < FDIM; k0 += 64) {
    __syncthreads();
    *(s16x8*)&As[sr * LDSW + cg * 16]     = ra0;
    *(s16x8*)&As[sr * LDSW + cg * 16 + 8] = ra1;
    *(s16x8*)&Bs[srb * LDSW + cgb * 8]    = rb;
    if (k0 + 64 < FDIM) {                  // prefetch next chunk (overlaps MFMA)
      ra0 = *(const s16x8*)(pa + k0 + 64);
      ra1 = *(const s16x8*)(pa + k0 + 72);
      rb  = *(const s16x8*)(pb + k0 + 64);
    }
    __syncthreads();
#pragma unroll
    for (int koff = 0; koff < 64; koff += 32) {
      s16x8 af0 = *(s16x8*)&As[(wm + m16) * LDSW + koff + q * 8];
      s16x8 af1 = *(s16x8*)&As[(wm + 16 + m16) * LDSW + koff + q * 8];
      s16x8 bf0 = *(s16x8*)&Bs[(wn + m16) * LDSW + koff + q * 8];
      acc[0] = __builtin_amdgcn_mfma_f32_16x16x32_bf16(af0, bf0, acc[0], 0, 0, 0);
      acc[1] = __builtin_amdgcn_mfma_f32_16x16x32_bf16(af1, bf0, acc[1], 0, 0, 0);
    }
  }
  // epilogue: D map col(n)=lane&15, row(m)=q*4+reg; rows contiguous in PRBT/PCT
#pragma unroll
  for (int rt = 0; rt < 2; ++rt) {
    const int hn = bn + wn + m16;          // 0..511
    const int row0 = bm + wm + rt * 16 + q * 4;
    if (hn < 256) {
      const float bias = b1[hn];
      float4 v = make_float4(acc[rt][0] + bias, acc[rt][1] + bias,
                             acc[rt][2] + bias, acc[rt][3] + bias);
      *(float4*)&PRBT[hn * ROWS + row0] = v;
    } else {
      float4 v = make_float4(acc[rt][0], acc[rt][1], acc[rt][2], acc[rt][3]);
      *(float4*)&PCT[(hn - 256) * ROWS + row0] = v;
    }
  }
}

// ---------- K2: edge + 13-bit count/value histogram ----------
// tile 64(i) x 32(j), 512 threads (8 waves/CU), 2x2 per thread; grid 256.
__global__ __launch_bounds__(512) void k_edge(const float* __restrict__ PRBT,
                                              const float* __restrict__ PCT,
                                              const float* __restrict__ W2,
                                              const float* __restrict__ b2,
                                              float* __restrict__ edge,
                                              unsigned* __restrict__ gcount,
                                              float* __restrict__ gvsum) {
  const int b = blockIdx.z;
  const int i0 = blockIdx.y * 64, j0 = blockIdx.x * 32;
  const int t = threadIdx.x;
  __shared__ float prs[64][68];        // [h][i]
  __shared__ float pcs[64][36];        // [h][j]
  __shared__ float w2s[HDIM];
  __shared__ unsigned lhc[NBIN / 2];   // packed 2x16-bit counts (16 KB)
  __shared__ float lhv[NBIN];          // value sums (32 KB)
  if (t < HDIM) w2s[t] = W2[t];
#pragma unroll
  for (int i = 0; i < 2; ++i) ((uint4*)lhc)[t + i * 512] = make_uint4(0u, 0u, 0u, 0u);
#pragma unroll
  for (int i = 0; i < 4; ++i) ((float4*)lhv)[t + i * 512] = make_float4(0.f, 0.f, 0.f, 0.f);
  const float bias = b2[0];
  const int tmi = t >> 4, tnj = t & 15;     // i-pair 0..31, j-pair 0..15
  float acc[2][2] = {};
  for (int h0 = 0; h0 < HDIM; h0 += 64) {
    __syncthreads();
#pragma unroll
    for (int s = 0; s < 2; ++s) {           // prs: 64h x 64i (1024 float4)
      int idx = t + s * 512;
      int hh = idx >> 4, ig = idx & 15;
      *(float4*)&prs[hh][ig * 4] =
          *(const float4*)&PRBT[(h0 + hh) * ROWS + b * NN + i0 + ig * 4];
    }
    {                                       // pcs: 64h x 32j (512 float4)
      int hh = t >> 3, jg = t & 7;
      *(float4*)&pcs[hh][jg * 4] =
          *(const float4*)&PCT[(h0 + hh) * ROWS + b * NN + j0 + jg * 4];
    }
    __syncthreads();
#pragma unroll 8
    for (int h = 0; h < 64; ++h) {
      const float w = w2s[h0 + h];
      const float2 a = *(const float2*)&prs[h][tmi * 2];
      const float2 c = *(const float2*)&pcs[h][tnj * 2];
      acc[0][0] += fmaxf(a.x + c.x, 0.f) * w;
      acc[0][1] += fmaxf(a.x + c.y, 0.f) * w;
      acc[1][0] += fmaxf(a.y + c.x, 0.f) * w;
      acc[1][1] += fmaxf(a.y + c.y, 0.f) * w;
    }
  }
  // write edge + histogram (values in registers)
  const int ibase = i0 + tmi * 2, jbase = j0 + tnj * 2;
#pragma unroll
  for (int i = 0; i < 2; ++i) {
    float2 v = make_float2(acc[i][0] + bias, acc[i][1] + bias);
    *(float2*)&edge[b * NSQ + (ibase + i) * NN + jbase] = v;
    float ex = __expf(v.x * 2.f), ey = __expf(v.y * 2.f);
    unsigned bx = fkey(v.x) >> 19, by = fkey(v.y) >> 19;
    atomicAdd(&lhc[bx >> 1], 1u << ((bx & 1) * 16));
    atomicAdd(&lhv[bx], ex);
    atomicAdd(&lhc[by >> 1], 1u << ((by & 1) * 16));
    atomicAdd(&lhv[by], ey);
  }
  __syncthreads();
  unsigned* gc = gcount + b * NBIN;
  float* gv = gvsum + b * NBIN;
#pragma unroll
  for (int i = 0; i < 8; ++i) {
    const int idx = t + i * 512;
    unsigned wv = lhc[idx];
    if (wv) {
      unsigned lo = wv & 0xFFFFu, hi = wv >> 16;
      if (lo) atomicAdd(&gc[2 * idx], lo);
      if (hi) atomicAdd(&gc[2 * idx + 1], hi);
    }
  }
#pragma unroll
  for (int i = 0; i < 16; ++i) {
    const int idx = t + i * 512;
    float vv = lhv[idx];
    if (vv != 0.f) atomicAdd(&gv[idx], vv);
  }
}

// ---------- K3: scan (inline) + soft + causal + conf ----------
__global__ __launch_bounds__(256) void k_out(const float* __restrict__ edge,
                                             const unsigned* __restrict__ gcount,
                                             const float* __restrict__ gvsum,
                                             float* __restrict__ soft,
                                             float* __restrict__ causal,
                                             float* __restrict__ conf) {
  const int b = blockIdx.y;
  const int t = threadIdx.x;
  __shared__ unsigned S[256];
  __shared__ float V[256];
  __shared__ unsigned ou[1];
  __shared__ float of[3];
  const unsigned* hc = gcount + b * NBIN;
  const float* hv = gvsum + b * NBIN;
  unsigned cs = 0; float vs = 0.f;
  for (int i = 0; i < 32; ++i) { cs += hc[t * 32 + i]; vs += hv[t * 32 + i]; }
  S[t] = cs; V[t] = vs;
  __syncthreads();
  for (int off = 1; off < 256; off <<= 1) {     // inclusive suffix sums
    unsigned su = (t + off < 256) ? S[t + off] : 0u;
    float vu = (t + off < 256) ? V[t + off] : 0.f;
    __syncthreads();
    S[t] += su; V[t] += vu;
    __syncthreads();
  }
  if (t == 0) of[2] = V[0];                      // Z = total exp sum
  const int above = (int)(S[t] - cs);
  if (above < KSEL && (int)S[t] >= KSEL) {       // exactly one thread
    int cum = above;
    float vcum = V[t] - vs;
    for (int i = 31; i >= 0; --i) {
      unsigned c = hc[t * 32 + i];
      float v = hv[t * 32 + i];
      cum += (int)c;
      if (cum >= KSEL) { ou[0] = (unsigned)(t * 32 + i); of[0] = vcum; of[1] = v; break; }
      vcum += v;
    }
  }
  __syncthreads();
  const float th = finv(ou[0] << 19);            // 13-bit truncated threshold
  const float Z = of[2];
  const float invZ = 1.f / Z;
  const float msum = (of[0] + of[1]) * invZ;     // masked soft sum (bin-exact)
  const float invD = 1.f / (msum + 1e-12f);
  const int off = b * NSQ + blockIdx.x * 2048 + t * 8;
#pragma unroll
  for (int i = 0; i < 8; i += 4) {
    float4 v = *(const float4*)&edge[off + i];
    float4 o = make_float4(__expf(v.x * 2.f) * invZ, __expf(v.y * 2.f) * invZ,
                           __expf(v.z * 2.f) * invZ, __expf(v.w * 2.f) * invZ);
    *(float4*)&soft[off + i] = o;
    float cx = v.x >= th ? o.x * invD : 0.f;
    float cy = v.y >= th ? o.y * invD : 0.f;
    float cz = v.z >= th ? o.z * invD : 0.f;
    float cw = v.w >= th ? o.w * invD : 0.f;
    *(float4*)&causal[off + i] = make_float4(cx, cy, cz, cw);
    *(float4*)&conf[off + i]   = make_float4(1.f - cx, 1.f - cy, 1.f - cz, 1.f - cw);
  }
}

extern "C" void kernel_launch(void* const* d_in, const int* in_sizes, int n_in,
                              void* d_out, int out_size, void* d_ws, size_t ws_size,
                              hipStream_t stream) {
  const float* x  = (const float*)d_in[0];
  const float* W1 = (const float*)d_in[1];
  const float* b1 = (const float*)d_in[2];
  const float* W2 = (const float*)d_in[3];
  const float* b2 = (const float*)d_in[4];

  float* out = (float*)d_out;
  float* causal = out;
  float* conf   = out + 1 * 524288;
  float* edge   = out + 2 * 524288;
  float* soft   = out + 3 * 524288;

  float* ws = (float*)d_ws;
  float*          PRBT   = ws;                                // 524288 floats
  float*          PCT    = ws + 524288;                       // 524288 floats
  unsigned short* XB     = (unsigned short*)(ws + 1048576);   // 2097152 bf16
  unsigned short* W1B    = (unsigned short*)(ws + 2097152);   // 524288 bf16
  unsigned*       gcount = (unsigned*)(ws + 2359296);         // 8*8192 uints
  float*          gvsum  = (float*)(ws + 2424832);            // 8*8192 floats (zero: 131072 words)

  k_prep<<<1408, 256, 0, stream>>>(x, W1, XB, W1B, gcount);
  k_gemm<<<dim3(32, 16), 256, 0, stream>>>(XB, W1B, b1, PRBT, PCT);
  k_edge<<<dim3(8, 4, 8), 512, 0, stream>>>(PRBT, PCT, W2, b2, edge, gcount, gvsum);
  k_out<<<dim3(32, 8), 256, 0, stream>>>(edge, gcount, gvsum, soft, causal, conf);
}